// Round 1
// baseline (783.443 us; speedup 1.0000x reference)
//
#include <hip/hip_runtime.h>

#define B_  32
#define S_  2048
#define H_  1024
#define A_  256
#define L_  10

typedef unsigned short u16;
typedef __bf16 bfv8 __attribute__((ext_vector_type(8)));
typedef float  f32x4 __attribute__((ext_vector_type(4)));

__device__ __forceinline__ u16 f2bf(float f) {
    unsigned int u = __builtin_bit_cast(unsigned int, f);
    u += 0x7FFFu + ((u >> 16) & 1u);            // RNE
    return (u16)(u >> 16);
}
__device__ __forceinline__ float bf2f(u16 h) {
    unsigned int u = ((unsigned int)h) << 16;
    return __builtin_bit_cast(float, u);
}

// ---------------------------------------------------------------------------
// Pack W1 [L][H][A] and W2 [L][A][H] into MFMA B-fragment order, split hi/lo.
// Tile = (kt:32 x nt:16), 512 bf16/tile, slot = lane*8 + i,
//   k = kt*32 + (lane>>4)*8 + i,  n = nt*16 + (lane&15).
// W1: per-lid tiles = 32(kt) x 16(nt);  W2: per-lid tiles = 8(kt) x 64(nt).
// ---------------------------------------------------------------------------
__global__ __launch_bounds__(256) void pack_weights(
    const float* __restrict__ W1, const float* __restrict__ W2,
    u16* __restrict__ w1h, u16* __restrict__ w1l,
    u16* __restrict__ w2h, u16* __restrict__ w2l)
{
    int tid = blockIdx.x * 256 + threadIdx.x;   // 2 * 10 * 262144 threads
    int which = tid >= L_ * 262144;
    int p = which ? tid - L_ * 262144 : tid;
    int i = p & 7, lane = (p >> 3) & 63, lid = p >> 18;
    int kk = ((lane >> 4) << 3) + i;
    const float* src; u16 *dh, *dl;
    if (!which) {
        int ntkt = (p >> 9) & 511;              // kt*16 + nt
        int nt = ntkt & 15, kt = ntkt >> 4;
        int k = kt * 32 + kk, n = nt * 16 + (lane & 15);
        src = W1 + ((size_t)lid * H_ + k) * A_ + n;
        dh = w1h; dl = w1l;
    } else {
        int ntkt = (p >> 9) & 511;              // kt*64 + nt
        int nt = ntkt & 63, kt = ntkt >> 6;
        int k = kt * 32 + kk, n = nt * 16 + (lane & 15);
        src = W2 + ((size_t)lid * A_ + k) * H_ + n;
        dh = w2h; dl = w2l;
    }
    float w = *src;
    u16 hi = f2bf(w);
    u16 lo = f2bf(w - bf2f(hi));
    dh[p] = hi; dl[p] = lo;
}

// ---------------------------------------------------------------------------
// GEMM1: h = relu(X @ W1 + b1), split-bf16 3-product MFMA.
// Block: 64 rows x 256 cols, 512 thr (8 waves: 2M x 4N, wave tile 32x64).
// Output: h packed to A-fragment layout hi/lo planes:
//   [b][mtile(S/16)][kt(8)][slot(512)],  slot: lane*8+i ->
//   row = mtile*16 + (lane&15), k = kt*32 + (lane>>4)*8 + i.
// ---------------------------------------------------------------------------
__global__ __launch_bounds__(512) void k_gemm1(
    const float* __restrict__ X, const int* __restrict__ langs,
    const float* __restrict__ b1,
    const u16* __restrict__ w1h, const u16* __restrict__ w1l,
    u16* __restrict__ hh, u16* __restrict__ hl)
{
    __shared__ union {
        struct { u16 xh[64][72]; u16 xl[64][72]; } st;   // 18432 B, pad 72 vs bank conflicts
        float hbuf[64][256];                              // 65536 B (XOR-swizzled cols)
    } lds;

    const int b   = blockIdx.y;
    const int s0  = blockIdx.x * 64;
    const int lid = langs[b];
    const int t    = threadIdx.x;
    const int lane = t & 63, wid = t >> 6;
    const int wm = wid >> 2, wn = wid & 3;     // wave rows wm*32.., cols wn*64..
    const int lr = lane & 15, lg = lane >> 4;

    f32x4 acc[2][4];
    #pragma unroll
    for (int mf = 0; mf < 2; ++mf)
        #pragma unroll
        for (int nf = 0; nf < 4; ++nf) acc[mf][nf] = f32x4{0.f, 0.f, 0.f, 0.f};

    const float* Xb = X + ((size_t)(b * S_ + s0)) * H_;

    #pragma unroll 1
    for (int kc = 0; kc < 16; ++kc) {          // K chunks of 64
        { // stage 64x64 fp32 -> hi/lo bf16 LDS
            int row = t >> 3, cg = (t & 7) * 8;
            const float* src = Xb + (size_t)row * H_ + kc * 64 + cg;
            float4 v0 = *(const float4*)(src);
            float4 v1 = *(const float4*)(src + 4);
            float vv[8] = {v0.x, v0.y, v0.z, v0.w, v1.x, v1.y, v1.z, v1.w};
            u16* dh = &lds.st.xh[row][cg];
            u16* dl = &lds.st.xl[row][cg];
            #pragma unroll
            for (int j = 0; j < 8; ++j) {
                u16 h = f2bf(vv[j]);
                dh[j] = h; dl[j] = f2bf(vv[j] - bf2f(h));
            }
        }
        __syncthreads();
        #pragma unroll
        for (int kl = 0; kl < 2; ++kl) {       // two 32-k steps
            bfv8 ah[2], al[2];
            #pragma unroll
            for (int mf = 0; mf < 2; ++mf) {
                int row = wm * 32 + mf * 16 + lr;
                int co  = kl * 32 + lg * 8;
                ah[mf] = *(const bfv8*)&lds.st.xh[row][co];
                al[mf] = *(const bfv8*)&lds.st.xl[row][co];
            }
            int ktg = kc * 2 + kl;
            #pragma unroll
            for (int nf = 0; nf < 4; ++nf) {
                int nt = wn * 4 + nf;
                size_t tb = (((size_t)lid * 32 + ktg) * 16 + nt) * 512 + lane * 8;
                bfv8 bh = *(const bfv8*)(w1h + tb);
                bfv8 bl = *(const bfv8*)(w1l + tb);
                #pragma unroll
                for (int mf = 0; mf < 2; ++mf) {
                    acc[mf][nf] = __builtin_amdgcn_mfma_f32_16x16x32_bf16(ah[mf], bh, acc[mf][nf], 0, 0, 0);
                    acc[mf][nf] = __builtin_amdgcn_mfma_f32_16x16x32_bf16(ah[mf], bl, acc[mf][nf], 0, 0, 0);
                    acc[mf][nf] = __builtin_amdgcn_mfma_f32_16x16x32_bf16(al[mf], bh, acc[mf][nf], 0, 0, 0);
                }
            }
        }
        __syncthreads();
    }

    // epilogue: bias + relu -> swizzled LDS hbuf
    #pragma unroll
    for (int mf = 0; mf < 2; ++mf)
        #pragma unroll
        for (int nf = 0; nf < 4; ++nf) {
            int col = wn * 64 + nf * 16 + lr;
            float bias = b1[lid * A_ + col];
            #pragma unroll
            for (int r = 0; r < 4; ++r) {
                int row = wm * 32 + mf * 16 + lg * 4 + r;
                float v = acc[mf][nf][r] + bias;
                v = v > 0.f ? v : 0.f;
                lds.hbuf[row][col ^ ((row & 7) << 2)] = v;
            }
        }
    __syncthreads();

    // pack h (hi/lo bf16, A-frag order) -> global, coalesced
    size_t base = (((size_t)b * 128 + (s0 >> 4)) * 8) * 512;
    #pragma unroll
    for (int j = 0; j < 32; ++j) {
        int q  = t + j * 512;
        int i  = q & 7, lp = (q >> 3) & 63, kt = (q >> 9) & 7, mt = q >> 12;
        int rowl = mt * 16 + (lp & 15);
        int k    = kt * 32 + ((lp >> 4) << 3) + i;
        float v = lds.hbuf[rowl][k ^ ((rowl & 7) << 2)];
        u16 hi = f2bf(v);
        u16 lo = f2bf(v - bf2f(hi));
        hh[base + q] = hi;
        hl[base + q] = lo;
    }
}

// ---------------------------------------------------------------------------
// GEMM2 + bias + residual + LayerNorm + gamma/beta, fused.
// Block: 64 rows x 1024 cols, 512 thr (8 waves: 2M x 4N, wave tile 32x256).
// ---------------------------------------------------------------------------
__global__ __launch_bounds__(512) void k_gemm2(
    const float* __restrict__ X, const int* __restrict__ langs,
    const float* __restrict__ b2, const float* __restrict__ gamma,
    const float* __restrict__ beta,
    const u16* __restrict__ w2h, const u16* __restrict__ w2l,
    const u16* __restrict__ hh, const u16* __restrict__ hl,
    float* __restrict__ out)
{
    __shared__ float part[64][4][2];
    __shared__ float mrstd[64][2];

    const int b   = blockIdx.y;
    const int s0  = blockIdx.x * 64;
    const int lid = langs[b];
    const int t    = threadIdx.x;
    const int lane = t & 63, wid = t >> 6;
    const int wm = wid >> 2, wn = wid & 3;     // rows wm*32.., cols wn*256..
    const int lr = lane & 15, lg = lane >> 4;

    f32x4 acc[2][16];
    #pragma unroll
    for (int mf = 0; mf < 2; ++mf)
        #pragma unroll
        for (int nf = 0; nf < 16; ++nf) acc[mf][nf] = f32x4{0.f, 0.f, 0.f, 0.f};

    size_t habase = (((size_t)b * 128 + (s0 >> 4) + wm * 2) * 8) * 512;

    #pragma unroll 1
    for (int kt = 0; kt < 8; ++kt) {           // K = 256, 32 per step
        bfv8 ah[2], al[2];
        #pragma unroll
        for (int mf = 0; mf < 2; ++mf) {
            size_t tb = habase + ((size_t)mf * 8 + kt) * 512 + lane * 8;
            ah[mf] = *(const bfv8*)(hh + tb);
            al[mf] = *(const bfv8*)(hl + tb);
        }
        #pragma unroll
        for (int nf = 0; nf < 16; ++nf) {
            int nt = wn * 16 + nf;
            size_t tb = (((size_t)lid * 8 + kt) * 64 + nt) * 512 + lane * 8;
            bfv8 bh = *(const bfv8*)(w2h + tb);
            bfv8 bl = *(const bfv8*)(w2l + tb);
            #pragma unroll
            for (int mf = 0; mf < 2; ++mf) {
                acc[mf][nf] = __builtin_amdgcn_mfma_f32_16x16x32_bf16(ah[mf], bh, acc[mf][nf], 0, 0, 0);
                acc[mf][nf] = __builtin_amdgcn_mfma_f32_16x16x32_bf16(ah[mf], bl, acc[mf][nf], 0, 0, 0);
                acc[mf][nf] = __builtin_amdgcn_mfma_f32_16x16x32_bf16(al[mf], bh, acc[mf][nf], 0, 0, 0);
            }
        }
    }

    // bias + residual; accumulate row sums for LN
    const float* Xb = X + ((size_t)(b * S_ + s0)) * H_;
    float s1[2][4], s2[2][4];
    #pragma unroll
    for (int mf = 0; mf < 2; ++mf)
        #pragma unroll
        for (int r = 0; r < 4; ++r) { s1[mf][r] = 0.f; s2[mf][r] = 0.f; }

    #pragma unroll
    for (int mf = 0; mf < 2; ++mf)
        #pragma unroll
        for (int nf = 0; nf < 16; ++nf) {
            int col = wn * 256 + nf * 16 + lr;
            float bb = b2[lid * H_ + col];
            #pragma unroll
            for (int r = 0; r < 4; ++r) {
                int row = wm * 32 + mf * 16 + lg * 4 + r;
                float x = acc[mf][nf][r] + bb + Xb[(size_t)row * H_ + col];
                acc[mf][nf][r] = x;
                s1[mf][r] += x; s2[mf][r] += x * x;
            }
        }

    // reduce across the 16 column-lanes (stays within 16-lane groups)
    #pragma unroll
    for (int mf = 0; mf < 2; ++mf)
        #pragma unroll
        for (int r = 0; r < 4; ++r) {
            float a = s1[mf][r], c = s2[mf][r];
            #pragma unroll
            for (int m = 1; m < 16; m <<= 1) { a += __shfl_xor(a, m); c += __shfl_xor(c, m); }
            if (lr == 0) {
                int row = wm * 32 + mf * 16 + lg * 4 + r;
                part[row][wn][0] = a; part[row][wn][1] = c;
            }
        }
    __syncthreads();
    if (t < 64) {
        float a = part[t][0][0] + part[t][1][0] + part[t][2][0] + part[t][3][0];
        float c = part[t][0][1] + part[t][1][1] + part[t][2][1] + part[t][3][1];
        float mean = a * (1.f / 1024.f);
        float var  = c * (1.f / 1024.f) - mean * mean;
        mrstd[t][0] = mean;
        mrstd[t][1] = rsqrtf(var + 1e-5f);
    }
    __syncthreads();

    float* ob = out + ((size_t)(b * S_ + s0)) * H_;
    #pragma unroll
    for (int nf = 0; nf < 16; ++nf) {
        int col = wn * 256 + nf * 16 + lr;
        float g  = gamma[lid * H_ + col];
        float bt = beta[lid * H_ + col];
        #pragma unroll
        for (int mf = 0; mf < 2; ++mf)
            #pragma unroll
            for (int r = 0; r < 4; ++r) {
                int row = wm * 32 + mf * 16 + lg * 4 + r;
                float x = acc[mf][nf][r];
                ob[(size_t)row * H_ + col] = (x - mrstd[row][0]) * mrstd[row][1] * g + bt;
            }
    }
}

// ---------------------------------------------------------------------------
extern "C" void kernel_launch(void* const* d_in, const int* in_sizes, int n_in,
                              void* d_out, int out_size, void* d_ws, size_t ws_size,
                              hipStream_t stream)
{
    const float* X     = (const float*)d_in[0];
    const int*   langs = (const int*)  d_in[1];
    const float* W1    = (const float*)d_in[2];
    const float* b1    = (const float*)d_in[3];
    const float* W2    = (const float*)d_in[4];
    const float* b2    = (const float*)d_in[5];
    const float* gamma = (const float*)d_in[6];
    const float* beta  = (const float*)d_in[7];
    float* out = (float*)d_out;

    char* ws = (char*)d_ws;
    u16* w1h = (u16*)(ws);                     //  5,242,880 B each plane
    u16* w1l = (u16*)(ws + 5242880);
    u16* w2h = (u16*)(ws + 10485760);
    u16* w2l = (u16*)(ws + 15728640);
    u16* hh  = (u16*)(ws + 20971520);          // 33,554,432 B each plane
    u16* hl  = (u16*)(ws + 54525952);          // total 88,080,384 B

    hipLaunchKernelGGL(pack_weights, dim3(20480), dim3(256), 0, stream,
                       W1, W2, w1h, w1l, w2h, w2l);
    hipLaunchKernelGGL(k_gemm1, dim3(S_ / 64, B_), dim3(512), 0, stream,
                       X, langs, b1, w1h, w1l, hh, hl);
    hipLaunchKernelGGL(k_gemm2, dim3(S_ / 64, B_), dim3(512), 0, stream,
                       X, langs, b2, gamma, beta, w2h, w2l, hh, hl, out);
}